// Round 5
// baseline (424.728 us; speedup 1.0000x reference)
//
#include <hip/hip_runtime.h>
#include <hip/hip_bf16.h>

#define N_NODES 100000
#define E_EDGES 1600000
#define ETOT    1700000   // E + N self-loops
#define NB_SCAN 391       // ceil(N/256)
#define F_IN    128
#define HC      64
#define OUT_C   40
#define NEG_SLOPE 0.2f
#define BN_EPS  1e-5f

// R11: XCD-pinned destination banding for CSR build. 8 bands, band =
// blockIdx & 7 -> consecutive blocks round-robin the 8 XCDs, so ALL blocks
// of band b run on XCD b. Band b's col window (850 KB) + cursor (50 KB)
// stay dirty in that single XCD's 4 MB L2 -> full-line evictions. R10 PMC
// showed the 4-band version wrote 85 MB HBM for a 6.8 MB col array (partial
// lines dirtied in multiple non-shared L2s). Mapping is a perf heuristic
// only; correctness is unaffected if dispatch order changes.
#define BAND_SZ 12500
#define N_BAND  8
#define SLICE_E 8192      // edges per block-slice
#define N_SLICE 196       // ceil(E_EDGES / SLICE_E)

// fp32 param block layout (element offsets)
#define P_W1   0
#define P_AS1  8192
#define P_AD1  8256
#define P_B1   8320
#define P_BNG  8384
#define P_BNB  8448
#define P_BNM  8512
#define P_BNV  8576
#define P_W2   8640
#define P_AS2  12736
#define P_AD2  12800
#define P_B2   12864
#define P_WF   12928
#define P_BF   15488
#define P_TOT  15528

typedef __attribute__((ext_vector_type(8))) short short8;
typedef __attribute__((ext_vector_type(4))) float floatx4;

__device__ __forceinline__ unsigned short f2bf(float f) {   // RNE fp32->bf16
    unsigned int u = __float_as_uint(f);
    unsigned int r = u + 0x7FFFu + ((u >> 16) & 1u);
    return (unsigned short)(r >> 16);
}

// ---------------- dtype detection ----------------
__global__ __launch_bounds__(64) void detect_kernel(const unsigned short* __restrict__ x,
                                                    int* __restrict__ flag) {
    int t = threadIdx.x;
    bool huge = false;
#pragma unroll
    for (int i = 0; i < 4; ++i) {
        unsigned short u = x[(t * 4 + i) * 2];
        float v = __uint_as_float(((unsigned int)u) << 16);
        if (!(fabsf(v) < 1e4f)) huge = true;
    }
    unsigned long long b = __ballot(huge);
    if (t == 0) *flag = (b != 0ull) ? 1 : 0;             // 1 => fp32 tensors
}

// ---------------- small-param conversion to fp32 ----------------
struct CvtArgs { const void* ptr[14]; int len[14]; };

__global__ __launch_bounds__(256) void cvt_params_kernel(CvtArgs a,
                                                         const int* __restrict__ flag,
                                                         float* __restrict__ dst) {
    int f = *flag;
    int i = blockIdx.x * 256 + threadIdx.x;
    if (i >= P_TOT) return;
    int k = 0, off = 0;
    while (i >= off + a.len[k]) { off += a.len[k]; ++k; }
    int j = i - off;
    float v = f ? ((const float*)a.ptr[k])[j]
                : __bfloat162float(((const __hip_bfloat16*)a.ptr[k])[j]);
    dst[i] = v;
}

// ---------------- W1/W2 -> bf16 MFMA B-fragment order ----------------
__global__ __launch_bounds__(256) void build_frags_kernel(const float* __restrict__ prm,
                                                          unsigned short* __restrict__ fw1,
                                                          unsigned short* __restrict__ fw2) {
    int i = blockIdx.x * 256 + threadIdx.x;
    if (i < 8192) {
        int j = i & 7, l = (i >> 3) & 63, q = (i >> 9) & 3, t = i >> 11;
        int k = q * 32 + (l >> 4) * 8 + j;
        int n = t * 16 + (l & 15);
        fw1[i] = f2bf(prm[P_W1 + k * 64 + n]);
    } else if (i < 12288) {
        int f = i - 8192;
        int j = f & 7, l = (f >> 3) & 63, q = (f >> 9) & 1, t = f >> 10;
        int k = q * 32 + (l >> 4) * 8 + j;
        int n = t * 16 + (l & 15);
        fw2[f] = f2bf(prm[P_W2 + k * 64 + n]);
    }
}

// ---------------- CSR build: banded histogram, nt edge reads ----------------
__global__ __launch_bounds__(256) void hist_kernel(const int* __restrict__ ei,
                                                   int* __restrict__ deg) {
    int band  = blockIdx.x & (N_BAND - 1);
    int slice = blockIdx.x / N_BAND;
    int blo = band * BAND_SZ, bhi = blo + BAND_SZ;
    const unsigned long long* dst2 = (const unsigned long long*)(ei + E_EDGES);
    int base4 = slice * (SLICE_E / 4);
#pragma unroll
    for (int it = 0; it < 8; ++it) {
        int i4 = base4 + it * 256 + threadIdx.x;
        if (i4 < E_EDGES / 4) {
            unsigned long long p0 = __builtin_nontemporal_load(&dst2[i4 * 2]);
            unsigned long long p1 = __builtin_nontemporal_load(&dst2[i4 * 2 + 1]);
            int d[4] = {(int)(p0 & 0xFFFFFFFFull), (int)(p0 >> 32),
                        (int)(p1 & 0xFFFFFFFFull), (int)(p1 >> 32)};
#pragma unroll
            for (int c = 0; c < 4; ++c)
                if (d[c] >= blo && d[c] < bhi) atomicAdd(&deg[d[c]], 1);
        }
    }
}

// parallel scan; degree counted as deg[i]+1 (self-loop folded in)
__global__ __launch_bounds__(256) void scanA_kernel(const int* __restrict__ deg,
                                                    int* __restrict__ bsum) {
    __shared__ int sm[256];
    int t = threadIdx.x;
    int i = blockIdx.x * 256 + t;
    sm[t] = (i < N_NODES) ? deg[i] + 1 : 0;
    __syncthreads();
    for (int off = 128; off > 0; off >>= 1) {
        if (t < off) sm[t] += sm[t + off];
        __syncthreads();
    }
    if (t == 0) bsum[blockIdx.x] = sm[0];
}

__global__ __launch_bounds__(512) void scanB_kernel(const int* __restrict__ bsum,
                                                    int* __restrict__ boff,
                                                    int* __restrict__ row_start) {
    __shared__ int sm[512];
    int t = threadIdx.x;
    int v = (t < NB_SCAN) ? bsum[t] : 0;
    sm[t] = v;
    __syncthreads();
    for (int off = 1; off < 512; off <<= 1) {
        int o = (t >= off) ? sm[t - off] : 0;
        __syncthreads();
        sm[t] += o;
        __syncthreads();
    }
    if (t < NB_SCAN) boff[t] = sm[t] - v;
    if (t == NB_SCAN - 1) row_start[N_NODES] = sm[t];   // == ETOT
}

__global__ __launch_bounds__(256) void scanC_kernel(const int* __restrict__ deg,
                                                    const int* __restrict__ boff,
                                                    int* __restrict__ row_start,
                                                    int* __restrict__ cursor,
                                                    int* __restrict__ col) {
    __shared__ int sm[256];
    int t = threadIdx.x;
    int i = blockIdx.x * 256 + t;
    int v = (i < N_NODES) ? deg[i] + 1 : 0;
    sm[t] = v;
    __syncthreads();
    for (int off = 1; off < 256; off <<= 1) {
        int o = (t >= off) ? sm[t - off] : 0;
        __syncthreads();
        sm[t] += o;
        __syncthreads();
    }
    if (i < N_NODES) {
        int excl = sm[t] - v + boff[blockIdx.x];
        row_start[i] = excl;
        cursor[i]    = excl + 1;   // slot 0 = self-loop
        col[excl]    = i;
    }
}

// ---------------- banded scatter, nt edge reads ----------------
__global__ __launch_bounds__(256) void scatter_kernel(const int* __restrict__ ei,
                                                      int* __restrict__ cursor,
                                                      int* __restrict__ col) {
    int band  = blockIdx.x & (N_BAND - 1);
    int slice = blockIdx.x / N_BAND;
    int blo = band * BAND_SZ, bhi = blo + BAND_SZ;
    const unsigned long long* dst2 = (const unsigned long long*)(ei + E_EDGES);
    int base4 = slice * (SLICE_E / 4);
#pragma unroll
    for (int it = 0; it < 8; ++it) {
        int i4 = base4 + it * 256 + threadIdx.x;
        if (i4 < E_EDGES / 4) {
            unsigned long long p0 = __builtin_nontemporal_load(&dst2[i4 * 2]);
            unsigned long long p1 = __builtin_nontemporal_load(&dst2[i4 * 2 + 1]);
            int d[4] = {(int)(p0 & 0xFFFFFFFFull), (int)(p0 >> 32),
                        (int)(p1 & 0xFFFFFFFFull), (int)(p1 >> 32)};
#pragma unroll
            for (int c = 0; c < 4; ++c) {
                if (d[c] >= blo && d[c] < bhi) {
                    int s = __builtin_nontemporal_load(ei + i4 * 4 + c);
                    int pos = atomicAdd(&cursor[d[c]], 1);
                    col[pos] = s;
                }
            }
        }
    }
}

__device__ __forceinline__ float leaky(float v) { return v > 0.f ? v : NEG_SLOPE * v; }

__device__ __forceinline__ float red64(float v) {
#pragma unroll
    for (int off = 32; off > 0; off >>= 1) v += __shfl_xor(v, off, 64);
    return v;
}
__device__ __forceinline__ float red16(float v) {
#pragma unroll
    for (int off = 8; off > 0; off >>= 1) v += __shfl_xor(v, off, 64);
    return v;
}

// ---------------- MFMA GEMM 1: h_bf[N,64] = x[N,128] @ W1, + fused alpha ----------------
__global__ __launch_bounds__(128) void gemm1_kernel(const void* __restrict__ x,
                                                    const unsigned short* __restrict__ fw1,
                                                    const float* __restrict__ prm,
                                                    const int* __restrict__ flag,
                                                    unsigned short* __restrict__ h_bf,
                                                    float* __restrict__ as_,
                                                    float* __restrict__ ad_) {
    __shared__ short lx[2 * 4 * 64 * 8];   // 8 KB
    int t = threadIdx.x;
    int f = *flag;
    int base = blockIdx.x * 32;

#pragma unroll
    for (int i = 0; i < 4; ++i) {
        int cid = i * 128 + t;
        int m = cid >> 4, c = cid & 15;
        int q = c >> 2, g = c & 3;
        int loff = (((m >> 4) * 4 + q) * 64 + g * 16 + (m & 15)) * 8;
        short8 s;
        if (f) {
            const float4* p = (const float4*)((const float*)x + ((size_t)(base + m) << 7) + (c << 3));
            float4 u0 = p[0], u1 = p[1];
            s[0] = (short)f2bf(u0.x); s[1] = (short)f2bf(u0.y);
            s[2] = (short)f2bf(u0.z); s[3] = (short)f2bf(u0.w);
            s[4] = (short)f2bf(u1.x); s[5] = (short)f2bf(u1.y);
            s[6] = (short)f2bf(u1.z); s[7] = (short)f2bf(u1.w);
        } else {
            s = *(const short8*)((const unsigned short*)x + ((size_t)(base + m) << 7) + (c << 3));
        }
        *(short8*)&lx[loff] = s;
    }
    __syncthreads();

    int w = t >> 6, lane = t & 63;
    short8 a[4];
#pragma unroll
    for (int q = 0; q < 4; ++q) a[q] = *(short8*)&lx[((w * 4 + q) * 64 + lane) * 8];

    const short8* bw = (const short8*)fw1;
    floatx4 acc[4];
#pragma unroll
    for (int tt = 0; tt < 4; ++tt) acc[tt] = (floatx4){0.f, 0.f, 0.f, 0.f};
#pragma unroll
    for (int tt = 0; tt < 4; ++tt) {
#pragma unroll
        for (int q = 0; q < 4; ++q) {
            short8 b = bw[(tt * 4 + q) * 64 + lane];
            acc[tt] = __builtin_amdgcn_mfma_f32_16x16x32_bf16(a[q], b, acc[tt], 0, 0, 0);
        }
    }

    int cl = lane & 15, grp = lane >> 4;
#pragma unroll
    for (int tt = 0; tt < 4; ++tt) {
#pragma unroll
        for (int r = 0; r < 4; ++r) {
            int node = base + w * 16 + grp * 4 + r;
            h_bf[(size_t)node * 64 + tt * 16 + cl] = f2bf(acc[tt][r]);
        }
    }

    float as0 = prm[P_AS1 + 0  + cl], as1 = prm[P_AS1 + 16 + cl],
          as2 = prm[P_AS1 + 32 + cl], as3 = prm[P_AS1 + 48 + cl];
    float ad0 = prm[P_AD1 + 0  + cl], ad1 = prm[P_AD1 + 16 + cl],
          ad2 = prm[P_AD1 + 32 + cl], ad3 = prm[P_AD1 + 48 + cl];
#pragma unroll
    for (int r = 0; r < 4; ++r) {
        float sh0 = red16(acc[0][r] * as0 + acc[1][r] * as1);
        float sh1 = red16(acc[2][r] * as2 + acc[3][r] * as3);
        float dh0 = red16(acc[0][r] * ad0 + acc[1][r] * ad1);
        float dh1 = red16(acc[2][r] * ad2 + acc[3][r] * ad3);
        if (cl == 0) {
            int node = base + w * 16 + grp * 4 + r;
            as_[node * 2] = sh0;  as_[node * 2 + 1] = sh1;
            ad_[node * 2] = dh0;  ad_[node * 2 + 1] = dh1;
        }
    }
}

// ---------------- MFMA GEMM 2: h_bf = x1_bf[N,64] @ W2, + fused alpha ----------------
__global__ __launch_bounds__(128) void gemm2_kernel(const unsigned short* __restrict__ x1_bf,
                                                    const unsigned short* __restrict__ fw2,
                                                    const float* __restrict__ prm,
                                                    unsigned short* __restrict__ h_bf,
                                                    float* __restrict__ as_,
                                                    float* __restrict__ ad_) {
    __shared__ short lx[2 * 2 * 64 * 8];   // 4 KB
    int t = threadIdx.x;
    int base = blockIdx.x * 32;

#pragma unroll
    for (int i = 0; i < 2; ++i) {
        int cid = i * 128 + t;
        int m = cid >> 3, c = cid & 7;
        int q = c >> 2, g = c & 3;
        int loff = (((m >> 4) * 2 + q) * 64 + g * 16 + (m & 15)) * 8;
        short8 s = *(const short8*)(x1_bf + ((size_t)(base + m) << 6) + (c << 3));
        *(short8*)&lx[loff] = s;
    }
    __syncthreads();

    int w = t >> 6, lane = t & 63;
    short8 a[2];
#pragma unroll
    for (int q = 0; q < 2; ++q) a[q] = *(short8*)&lx[((w * 2 + q) * 64 + lane) * 8];

    const short8* bw = (const short8*)fw2;
    floatx4 acc[4];
#pragma unroll
    for (int tt = 0; tt < 4; ++tt) acc[tt] = (floatx4){0.f, 0.f, 0.f, 0.f};
#pragma unroll
    for (int tt = 0; tt < 4; ++tt) {
#pragma unroll
        for (int q = 0; q < 2; ++q) {
            short8 b = bw[(tt * 2 + q) * 64 + lane];
            acc[tt] = __builtin_amdgcn_mfma_f32_16x16x32_bf16(a[q], b, acc[tt], 0, 0, 0);
        }
    }

    int cl = lane & 15, grp = lane >> 4;
#pragma unroll
    for (int tt = 0; tt < 4; ++tt) {
#pragma unroll
        for (int r = 0; r < 4; ++r) {
            int node = base + w * 16 + grp * 4 + r;
            h_bf[(size_t)node * 64 + tt * 16 + cl] = f2bf(acc[tt][r]);
        }
    }

    float as0 = prm[P_AS2 + 0  + cl], as1 = prm[P_AS2 + 16 + cl],
          as2 = prm[P_AS2 + 32 + cl], as3 = prm[P_AS2 + 48 + cl];
    float ad0 = prm[P_AD2 + 0  + cl], ad1 = prm[P_AD2 + 16 + cl],
          ad2 = prm[P_AD2 + 32 + cl], ad3 = prm[P_AD2 + 48 + cl];
#pragma unroll
    for (int r = 0; r < 4; ++r) {
        float sh0 = red16(acc[0][r] * as0 + acc[1][r] * as1);
        float sh1 = red16(acc[2][r] * as2 + acc[3][r] * as3);
        float dh0 = red16(acc[0][r] * ad0 + acc[1][r] * ad1);
        float dh1 = red16(acc[2][r] * ad2 + acc[3][r] * ad3);
        if (cl == 0) {
            int node = base + w * 16 + grp * 4 + r;
            as_[node * 2] = sh0;  as_[node * 2 + 1] = sh1;
            ad_[node * 2] = dh0;  ad_[node * 2 + 1] = dh1;
        }
    }
}

// halving slot-reduction: lane ends with channel k=(lane&7) summed over its
// octet's 8 slots. 7 shfl + 14 sel + 7 add (vs 24/24/7 full butterfly).
// All shuffles convergent.
__device__ __forceinline__ float slot_reduce(float acc[8], int lane) {
    int slot = lane & 7;
    bool b2 = (slot & 4) != 0;
#pragma unroll
    for (int q = 0; q < 4; ++q) {
        float send = b2 ? acc[q] : acc[q + 4];
        float recv = __shfl_xor(send, 4, 64);
        acc[q] = (b2 ? acc[q + 4] : acc[q]) + recv;
    }
    bool b1 = (slot & 2) != 0;
#pragma unroll
    for (int q = 0; q < 2; ++q) {
        float send = b1 ? acc[q] : acc[q + 2];
        float recv = __shfl_xor(send, 2, 64);
        acc[q] = (b1 ? acc[q + 2] : acc[q]) + recv;
    }
    bool b0 = (slot & 1) != 0;
    float send = b0 ? acc[0] : acc[1];
    float recv = __shfl_xor(send, 1, 64);
    return (b0 ? acc[1] : acc[0]) + recv;
}

// ---------------- aggregation core, slot-parallel, SHUFFLE-FREE ----------------
// R10 (confirmed win): each slot lane loads col[e] and as_[c*2+hi] DIRECTLY
// (4B broadcast across the 8 lanes sharing a slot) and recomputes its own
// head's exp. Deletes all round shuffles AND the entire red64: denominator =
// per-lane running sum + 3-op octet xor-reduce. DS ops per node ~31 -> ~10.
__device__ __forceinline__ float agg_core(const unsigned short* __restrict__ h_bf,
                                          const float* __restrict__ as_,
                                          const float* __restrict__ ad_,
                                          const int* __restrict__ col,
                                          int v, int rs, int re, int lane) {
    int deg  = re - rs;
    int slot = lane & 7;
    int cg   = lane >> 3;        // channel group: my 8 channels = cg*8..cg*8+7
    int hi   = cg >> 2;          // head owning my channels
    if (deg <= 64) {
        float advh = ad_[v * 2 + hi];
        const unsigned short* hb = h_bf + (cg << 3);
        int last = re - 1;       // >= rs always (self-loop)
        float acc[8] = {0.f,0.f,0.f,0.f,0.f,0.f,0.f,0.f};
        float sw = 0.f;

        auto block4 = [&](int koff) {
            int ce[4]; float av[4]; uint4 dv[4];
#pragma unroll
            for (int k = 0; k < 4; ++k) {
                int e = rs + koff + k * 8 + slot;
                ce[k] = col[e < last ? e : last];     // clamped: always valid
            }
#pragma unroll
            for (int k = 0; k < 4; ++k)
                dv[k] = *(const uint4*)(hb + ((size_t)ce[k] << 6));
#pragma unroll
            for (int k = 0; k < 4; ++k)
                av[k] = as_[ce[k] * 2 + hi];
#pragma unroll
            for (int k = 0; k < 4; ++k) {
                int e = rs + koff + k * 8 + slot;
                float w = (e <= last) ? __expf(leaky(av[k] + advh)) : 0.f;
                sw += w;
#pragma unroll
                for (int q = 0; q < 4; ++q) {
                    unsigned int dw = (&dv[k].x)[q];
                    acc[2 * q]     = fmaf(w, __uint_as_float(dw << 16),         acc[2 * q]);
                    acc[2 * q + 1] = fmaf(w, __uint_as_float(dw & 0xFFFF0000u), acc[2 * q + 1]);
                }
            }
        };
        block4(0);                       // covers deg <= 32 (99.98% of nodes)
        if (deg > 32) block4(32);        // rare tail, wave-uniform

        // denominator: sum over the octet's 8 slots (3 convergent shuffles)
        sw += __shfl_xor(sw, 1, 64);
        sw += __shfl_xor(sw, 2, 64);
        sw += __shfl_xor(sw, 4, 64);
        float rdh = 1.f / (sw + 1e-16f);

        return slot_reduce(acc, lane) * rdh;
    } else {
        int head = lane >> 5;
        float adv0 = ad_[v * 2], adv1 = ad_[v * 2 + 1];
        float advh = head ? adv1 : adv0;
        float s0 = 0.f, s1 = 0.f;
        for (int e = rs + lane; e < re; e += 64) {
            int s = col[e];
            float2 av = *(const float2*)&as_[s * 2];
            s0 += __expf(leaky(av.x + adv0));
            s1 += __expf(leaky(av.y + adv1));
        }
        s0 = red64(s0); s1 = red64(s1);
        float rdh = 1.f / ((head ? s1 : s0) + 1e-16f);
        float a0 = 0.f;
        for (int e = rs; e < re; ++e) {
            int s = col[e];
            float w = __expf(leaky(as_[s * 2 + head] + advh));
            unsigned short u = h_bf[(size_t)s * 64 + lane];
            a0 = fmaf(w, __uint_as_float(((unsigned int)u) << 16), a0);
        }
        return a0 * rdh;
    }
}

// ---------------- aggregation layer 1 (+bias, BN eval, ELU) -> x1_bf ----------------
__global__ __launch_bounds__(256, 6) void agg1_kernel(const unsigned short* __restrict__ h_bf,
                                                   const float* __restrict__ as_,
                                                   const float* __restrict__ ad_,
                                                   const int* __restrict__ row_start,
                                                   const int* __restrict__ col,
                                                   const float* __restrict__ bias,
                                                   const float* __restrict__ bn_g,
                                                   const float* __restrict__ bn_b,
                                                   const float* __restrict__ bn_m,
                                                   const float* __restrict__ bn_v,
                                                   unsigned short* __restrict__ x1_bf) {
    int t = threadIdx.x, wid = t >> 6, lane = t & 63;
    int v = blockIdx.x * 4 + wid;
    int rs = row_start[v], re = row_start[v + 1];
    float acc = agg_core(h_bf, as_, ad_, col, v, rs, re, lane);
    float r = acc + bias[lane];
    float scale = bn_g[lane] * rsqrtf(bn_v[lane] + BN_EPS);
    r = (r - bn_m[lane]) * scale + bn_b[lane];
    r = r > 0.f ? r : expm1f(r);   // ELU
    x1_bf[(size_t)v * 64 + lane] = f2bf(r);
}

// ---------------- agg layer 2 + JK max + fused projection -> out [N,40] ----------------
__global__ __launch_bounds__(256, 6) void agg2_kernel(const unsigned short* __restrict__ h_bf,
                                                   const float* __restrict__ as_,
                                                   const float* __restrict__ ad_,
                                                   const int* __restrict__ row_start,
                                                   const int* __restrict__ col,
                                                   const float* __restrict__ prm,
                                                   const unsigned short* __restrict__ x1_bf,
                                                   const int* __restrict__ flag,
                                                   void* __restrict__ out) {
    __shared__ float Wfs[2560];      // Wf[c*40+o] natural layout: lanes o stride-1 -> conflict-free
    __shared__ float xsh[4][64];
    int t = threadIdx.x;
#pragma unroll
    for (int i = 0; i < 10; ++i) Wfs[i * 256 + t] = prm[P_WF + i * 256 + t];

    int wid = t >> 6, lane = t & 63;
    int v = blockIdx.x * 4 + wid;
    int rs = row_start[v], re = row_start[v + 1];
    float acc = agg_core(h_bf, as_, ad_, col, v, rs, re, lane);
    float x2 = acc + prm[P_B2 + lane];
    unsigned short u = x1_bf[(size_t)v * 64 + lane];
    float x1v = __uint_as_float(((unsigned int)u) << 16);
    xsh[wid][lane] = fmaxf(x1v, x2);   // JumpingKnowledge max
    __syncthreads();

    if (t < 160) {                     // 4 nodes x 40 outputs
        int n = t / 40, o = t - n * 40;
        float po = 0.f;
#pragma unroll
        for (int c = 0; c < 64; c += 4) {
            po = fmaf(xsh[n][c],     Wfs[c * 40 + o],       po);
            po = fmaf(xsh[n][c + 1], Wfs[(c + 1) * 40 + o], po);
            po = fmaf(xsh[n][c + 2], Wfs[(c + 2) * 40 + o], po);
            po = fmaf(xsh[n][c + 3], Wfs[(c + 3) * 40 + o], po);
        }
        float r = po + prm[P_BF + o];
        size_t idx = (size_t)(blockIdx.x * 4 + n) * 40 + o;
        if (*flag) ((float*)out)[idx] = r;
        else ((__hip_bfloat16*)out)[idx] = __float2bfloat16(r);
    }
}

extern "C" void kernel_launch(void* const* d_in, const int* in_sizes, int n_in,
                              void* d_out, int out_size, void* d_ws, size_t ws_size,
                              hipStream_t stream) {
    (void)in_sizes; (void)n_in; (void)out_size; (void)ws_size;
    const void* node_feat = d_in[0];
    const int*  edge_idx  = (const int*)d_in[1];

    char* ws = (char*)d_ws;
    size_t off = 0;
    auto alloc = [&](size_t bytes) -> void* {
        void* p = ws + off;
        off += (bytes + 255) & ~(size_t)255;
        return p;
    };
    unsigned short* h_bf  = (unsigned short*)alloc((size_t)N_NODES * 64 * 2);  // 12.8 MB
    unsigned short* x1_bf = (unsigned short*)alloc((size_t)N_NODES * 64 * 2);  // 12.8 MB
    float* as_ = (float*)alloc((size_t)N_NODES * 2 * 4);
    float* ad_ = (float*)alloc((size_t)N_NODES * 2 * 4);
    int* deg       = (int*)alloc((size_t)N_NODES * 4);
    int* row_start = (int*)alloc((size_t)(N_NODES + 1) * 4);
    int* cursor    = (int*)alloc((size_t)N_NODES * 4);
    int* col       = (int*)alloc((size_t)ETOT * 4);         // 6.8 MB
    int* bsum      = (int*)alloc((size_t)NB_SCAN * 4);
    int* boff      = (int*)alloc((size_t)NB_SCAN * 4);
    float* prm     = (float*)alloc((size_t)P_TOT * 4);
    unsigned short* fw1 = (unsigned short*)alloc(8192 * 2);
    unsigned short* fw2 = (unsigned short*)alloc(4096 * 2);
    int* flag      = (int*)alloc(256);

    detect_kernel<<<1, 64, 0, stream>>>((const unsigned short*)node_feat, flag);
    CvtArgs ca;
    const int lens[14] = {8192, 64, 64, 64, 64, 64, 64, 64, 4096, 64, 64, 64, 2560, 40};
    for (int i = 0; i < 14; ++i) { ca.ptr[i] = d_in[i + 2]; ca.len[i] = lens[i]; }
    cvt_params_kernel<<<(P_TOT + 255) / 256, 256, 0, stream>>>(ca, flag, prm);
    build_frags_kernel<<<48, 256, 0, stream>>>(prm, fw1, fw2);

    // CSR build: XCD-pinned banded hist -> scan (+1 self-loop) -> banded scatter
    hipMemsetAsync(deg, 0, (size_t)N_NODES * 4, stream);
    hist_kernel<<<N_SLICE * N_BAND, 256, 0, stream>>>(edge_idx, deg);
    scanA_kernel<<<NB_SCAN, 256, 0, stream>>>(deg, bsum);
    scanB_kernel<<<1, 512, 0, stream>>>(bsum, boff, row_start);
    scanC_kernel<<<NB_SCAN, 256, 0, stream>>>(deg, boff, row_start, cursor, col);
    scatter_kernel<<<N_SLICE * N_BAND, 256, 0, stream>>>(edge_idx, cursor, col);

    gemm1_kernel<<<N_NODES / 32, 128, 0, stream>>>(node_feat, fw1, prm, flag,
                                                   h_bf, as_, ad_);
    agg1_kernel<<<N_NODES / 4, 256, 0, stream>>>(h_bf, as_, ad_, row_start, col,
                                                 prm + P_B1, prm + P_BNG, prm + P_BNB,
                                                 prm + P_BNM, prm + P_BNV, x1_bf);
    gemm2_kernel<<<N_NODES / 32, 128, 0, stream>>>(x1_bf, fw2, prm,
                                                   h_bf, as_, ad_);
    agg2_kernel<<<N_NODES / 4, 256, 0, stream>>>(h_bf, as_, ad_, row_start, col,
                                                 prm, x1_bf, flag, d_out);
}

// Round 6
// 382.410 us; speedup vs baseline: 1.1107x; 1.1107x over previous
//
#include <hip/hip_runtime.h>
#include <hip/hip_bf16.h>

#define N_NODES 100000
#define E_EDGES 1600000
#define ETOT    1700000   // E + N self-loops
#define NB_SCAN 391       // ceil(N/256)
#define EQ4     400000    // E_EDGES / 4
#define NB_EQ4  1563      // ceil(EQ4 / 256)
#define F_IN    128
#define HC      64
#define OUT_C   40
#define NEG_SLOPE 0.2f
#define BN_EPS  1e-5f

// fp32 param block layout (element offsets)
#define P_W1   0
#define P_AS1  8192
#define P_AD1  8256
#define P_B1   8320
#define P_BNG  8384
#define P_BNB  8448
#define P_BNM  8512
#define P_BNV  8576
#define P_W2   8640
#define P_AS2  12736
#define P_AD2  12800
#define P_B2   12864
#define P_WF   12928
#define P_BF   15488
#define P_TOT  15528

typedef __attribute__((ext_vector_type(8))) short short8;
typedef __attribute__((ext_vector_type(4))) float floatx4;

__device__ __forceinline__ unsigned short f2bf(float f) {   // RNE fp32->bf16
    unsigned int u = __float_as_uint(f);
    unsigned int r = u + 0x7FFFu + ((u >> 16) & 1u);
    return (unsigned short)(r >> 16);
}

// ---------------- dtype detection ----------------
__global__ __launch_bounds__(64) void detect_kernel(const unsigned short* __restrict__ x,
                                                    int* __restrict__ flag) {
    int t = threadIdx.x;
    bool huge = false;
#pragma unroll
    for (int i = 0; i < 4; ++i) {
        unsigned short u = x[(t * 4 + i) * 2];
        float v = __uint_as_float(((unsigned int)u) << 16);
        if (!(fabsf(v) < 1e4f)) huge = true;
    }
    unsigned long long b = __ballot(huge);
    if (t == 0) *flag = (b != 0ull) ? 1 : 0;             // 1 => fp32 tensors
}

// ---------------- small-param conversion to fp32 ----------------
struct CvtArgs { const void* ptr[14]; int len[14]; };

__global__ __launch_bounds__(256) void cvt_params_kernel(CvtArgs a,
                                                         const int* __restrict__ flag,
                                                         float* __restrict__ dst) {
    int f = *flag;
    int i = blockIdx.x * 256 + threadIdx.x;
    if (i >= P_TOT) return;
    int k = 0, off = 0;
    while (i >= off + a.len[k]) { off += a.len[k]; ++k; }
    int j = i - off;
    float v = f ? ((const float*)a.ptr[k])[j]
                : __bfloat162float(((const __hip_bfloat16*)a.ptr[k])[j]);
    dst[i] = v;
}

// ---------------- W1/W2 -> bf16 MFMA B-fragment order ----------------
__global__ __launch_bounds__(256) void build_frags_kernel(const float* __restrict__ prm,
                                                          unsigned short* __restrict__ fw1,
                                                          unsigned short* __restrict__ fw2) {
    int i = blockIdx.x * 256 + threadIdx.x;
    if (i < 8192) {
        int j = i & 7, l = (i >> 3) & 63, q = (i >> 9) & 3, t = i >> 11;
        int k = q * 32 + (l >> 4) * 8 + j;
        int n = t * 16 + (l & 15);
        fw1[i] = f2bf(prm[P_W1 + k * 64 + n]);
    } else if (i < 12288) {
        int f = i - 8192;
        int j = f & 7, l = (f >> 3) & 63, q = (f >> 9) & 1, t = f >> 10;
        int k = q * 32 + (l >> 4) * 8 + j;
        int n = t * 16 + (l & 15);
        fw2[f] = f2bf(prm[P_W2 + k * 64 + n]);
    }
}

// ---------------- CSR build, R12: rank-based, atomic-free scatter ----------------
// R11 post-mortem: scatter was NOT BW-bound (135 MB @ 83us = 1.6 TB/s, VALU 3%)
// -- it was serialized on the per-edge atomicAdd(cursor)->wait->store round
// trip. hist already pays for the SAME atomic and discards the return value.
// Keep it: rank[e] = atomicAdd(&deg[dst],1) IS the edge's slot within its row.
// Scatter then needs NO atomics: pos = row_start[dst]+1+rank[e]. Both passes
// read the edge stream once (banding removed: hist reads 51MB -> 6.4MB).
// Ranks stored 32-bit (16B/quad) so any degree is correct.
__global__ __launch_bounds__(256) void histrank_kernel(const int* __restrict__ ei,
                                                       int* __restrict__ deg,
                                                       int4* __restrict__ rank4) {
    int i4 = blockIdx.x * 256 + threadIdx.x;
    if (i4 >= EQ4) return;
    const unsigned long long* dst2 = (const unsigned long long*)(ei + E_EDGES);
    unsigned long long p0 = __builtin_nontemporal_load(&dst2[i4 * 2]);
    unsigned long long p1 = __builtin_nontemporal_load(&dst2[i4 * 2 + 1]);
    int d0 = (int)(p0 & 0xFFFFFFFFull), d1 = (int)(p0 >> 32);
    int d2 = (int)(p1 & 0xFFFFFFFFull), d3 = (int)(p1 >> 32);
    int4 r;
    r.x = atomicAdd(&deg[d0], 1);     // 4 independent atomics, all in flight
    r.y = atomicAdd(&deg[d1], 1);
    r.z = atomicAdd(&deg[d2], 1);
    r.w = atomicAdd(&deg[d3], 1);
    rank4[i4] = r;                    // coalesced 16B store
}

// parallel scan; degree counted as deg[i]+1 (self-loop folded in)
__global__ __launch_bounds__(256) void scanA_kernel(const int* __restrict__ deg,
                                                    int* __restrict__ bsum) {
    __shared__ int sm[256];
    int t = threadIdx.x;
    int i = blockIdx.x * 256 + t;
    sm[t] = (i < N_NODES) ? deg[i] + 1 : 0;
    __syncthreads();
    for (int off = 128; off > 0; off >>= 1) {
        if (t < off) sm[t] += sm[t + off];
        __syncthreads();
    }
    if (t == 0) bsum[blockIdx.x] = sm[0];
}

__global__ __launch_bounds__(512) void scanB_kernel(const int* __restrict__ bsum,
                                                    int* __restrict__ boff,
                                                    int* __restrict__ row_start) {
    __shared__ int sm[512];
    int t = threadIdx.x;
    int v = (t < NB_SCAN) ? bsum[t] : 0;
    sm[t] = v;
    __syncthreads();
    for (int off = 1; off < 512; off <<= 1) {
        int o = (t >= off) ? sm[t - off] : 0;
        __syncthreads();
        sm[t] += o;
        __syncthreads();
    }
    if (t < NB_SCAN) boff[t] = sm[t] - v;
    if (t == NB_SCAN - 1) row_start[N_NODES] = sm[t];   // == ETOT
}

__global__ __launch_bounds__(256) void scanC_kernel(const int* __restrict__ deg,
                                                    const int* __restrict__ boff,
                                                    int* __restrict__ row_start,
                                                    int* __restrict__ col) {
    __shared__ int sm[256];
    int t = threadIdx.x;
    int i = blockIdx.x * 256 + t;
    int v = (i < N_NODES) ? deg[i] + 1 : 0;
    sm[t] = v;
    __syncthreads();
    for (int off = 1; off < 256; off <<= 1) {
        int o = (t >= off) ? sm[t - off] : 0;
        __syncthreads();
        sm[t] += o;
        __syncthreads();
    }
    if (i < N_NODES) {
        int excl = sm[t] - v + boff[blockIdx.x];
        row_start[i] = excl;
        col[excl]    = i;              // slot 0 = self-loop
    }
}

// ---------------- atomic-free scatter: pure stream + independent stores ----------------
__global__ __launch_bounds__(256) void scatter_kernel(const int* __restrict__ ei,
                                                      const int4* __restrict__ rank4,
                                                      const int* __restrict__ row_start,
                                                      int* __restrict__ col) {
    int i4 = blockIdx.x * 256 + threadIdx.x;
    if (i4 >= EQ4) return;
    const unsigned long long* dst2 = (const unsigned long long*)(ei + E_EDGES);
    const unsigned long long* src2 = (const unsigned long long*)ei;
    unsigned long long p0 = __builtin_nontemporal_load(&dst2[i4 * 2]);
    unsigned long long p1 = __builtin_nontemporal_load(&dst2[i4 * 2 + 1]);
    unsigned long long q0 = __builtin_nontemporal_load(&src2[i4 * 2]);
    unsigned long long q1 = __builtin_nontemporal_load(&src2[i4 * 2 + 1]);
    int4 r = rank4[i4];
    int d0 = (int)(p0 & 0xFFFFFFFFull), d1 = (int)(p0 >> 32);
    int d2 = (int)(p1 & 0xFFFFFFFFull), d3 = (int)(p1 >> 32);
    int s0 = (int)(q0 & 0xFFFFFFFFull), s1 = (int)(q0 >> 32);
    int s2 = (int)(q1 & 0xFFFFFFFFull), s3 = (int)(q1 >> 32);
    int b0 = row_start[d0];            // 4 independent gathers (L2-resident)
    int b1 = row_start[d1];
    int b2 = row_start[d2];
    int b3 = row_start[d3];
    col[b0 + 1 + r.x] = s0;            // 4 independent stores, no round-trip
    col[b1 + 1 + r.y] = s1;
    col[b2 + 1 + r.z] = s2;
    col[b3 + 1 + r.w] = s3;
}

__device__ __forceinline__ float leaky(float v) { return v > 0.f ? v : NEG_SLOPE * v; }

__device__ __forceinline__ float red64(float v) {
#pragma unroll
    for (int off = 32; off > 0; off >>= 1) v += __shfl_xor(v, off, 64);
    return v;
}
__device__ __forceinline__ float red16(float v) {
#pragma unroll
    for (int off = 8; off > 0; off >>= 1) v += __shfl_xor(v, off, 64);
    return v;
}

// ---------------- MFMA GEMM 1: h_bf[N,64] = x[N,128] @ W1, + fused alpha ----------------
__global__ __launch_bounds__(128) void gemm1_kernel(const void* __restrict__ x,
                                                    const unsigned short* __restrict__ fw1,
                                                    const float* __restrict__ prm,
                                                    const int* __restrict__ flag,
                                                    unsigned short* __restrict__ h_bf,
                                                    float* __restrict__ as_,
                                                    float* __restrict__ ad_) {
    __shared__ short lx[2 * 4 * 64 * 8];   // 8 KB
    int t = threadIdx.x;
    int f = *flag;
    int base = blockIdx.x * 32;

#pragma unroll
    for (int i = 0; i < 4; ++i) {
        int cid = i * 128 + t;
        int m = cid >> 4, c = cid & 15;
        int q = c >> 2, g = c & 3;
        int loff = (((m >> 4) * 4 + q) * 64 + g * 16 + (m & 15)) * 8;
        short8 s;
        if (f) {
            const float4* p = (const float4*)((const float*)x + ((size_t)(base + m) << 7) + (c << 3));
            float4 u0 = p[0], u1 = p[1];
            s[0] = (short)f2bf(u0.x); s[1] = (short)f2bf(u0.y);
            s[2] = (short)f2bf(u0.z); s[3] = (short)f2bf(u0.w);
            s[4] = (short)f2bf(u1.x); s[5] = (short)f2bf(u1.y);
            s[6] = (short)f2bf(u1.z); s[7] = (short)f2bf(u1.w);
        } else {
            s = *(const short8*)((const unsigned short*)x + ((size_t)(base + m) << 7) + (c << 3));
        }
        *(short8*)&lx[loff] = s;
    }
    __syncthreads();

    int w = t >> 6, lane = t & 63;
    short8 a[4];
#pragma unroll
    for (int q = 0; q < 4; ++q) a[q] = *(short8*)&lx[((w * 4 + q) * 64 + lane) * 8];

    const short8* bw = (const short8*)fw1;
    floatx4 acc[4];
#pragma unroll
    for (int tt = 0; tt < 4; ++tt) acc[tt] = (floatx4){0.f, 0.f, 0.f, 0.f};
#pragma unroll
    for (int tt = 0; tt < 4; ++tt) {
#pragma unroll
        for (int q = 0; q < 4; ++q) {
            short8 b = bw[(tt * 4 + q) * 64 + lane];
            acc[tt] = __builtin_amdgcn_mfma_f32_16x16x32_bf16(a[q], b, acc[tt], 0, 0, 0);
        }
    }

    int cl = lane & 15, grp = lane >> 4;
#pragma unroll
    for (int tt = 0; tt < 4; ++tt) {
#pragma unroll
        for (int r = 0; r < 4; ++r) {
            int node = base + w * 16 + grp * 4 + r;
            h_bf[(size_t)node * 64 + tt * 16 + cl] = f2bf(acc[tt][r]);
        }
    }

    float as0 = prm[P_AS1 + 0  + cl], as1 = prm[P_AS1 + 16 + cl],
          as2 = prm[P_AS1 + 32 + cl], as3 = prm[P_AS1 + 48 + cl];
    float ad0 = prm[P_AD1 + 0  + cl], ad1 = prm[P_AD1 + 16 + cl],
          ad2 = prm[P_AD1 + 32 + cl], ad3 = prm[P_AD1 + 48 + cl];
#pragma unroll
    for (int r = 0; r < 4; ++r) {
        float sh0 = red16(acc[0][r] * as0 + acc[1][r] * as1);
        float sh1 = red16(acc[2][r] * as2 + acc[3][r] * as3);
        float dh0 = red16(acc[0][r] * ad0 + acc[1][r] * ad1);
        float dh1 = red16(acc[2][r] * ad2 + acc[3][r] * ad3);
        if (cl == 0) {
            int node = base + w * 16 + grp * 4 + r;
            as_[node * 2] = sh0;  as_[node * 2 + 1] = sh1;
            ad_[node * 2] = dh0;  ad_[node * 2 + 1] = dh1;
        }
    }
}

// ---------------- MFMA GEMM 2: h_bf = x1_bf[N,64] @ W2, + fused alpha ----------------
__global__ __launch_bounds__(128) void gemm2_kernel(const unsigned short* __restrict__ x1_bf,
                                                    const unsigned short* __restrict__ fw2,
                                                    const float* __restrict__ prm,
                                                    unsigned short* __restrict__ h_bf,
                                                    float* __restrict__ as_,
                                                    float* __restrict__ ad_) {
    __shared__ short lx[2 * 2 * 64 * 8];   // 4 KB
    int t = threadIdx.x;
    int base = blockIdx.x * 32;

#pragma unroll
    for (int i = 0; i < 2; ++i) {
        int cid = i * 128 + t;
        int m = cid >> 3, c = cid & 7;
        int q = c >> 2, g = c & 3;
        int loff = (((m >> 4) * 2 + q) * 64 + g * 16 + (m & 15)) * 8;
        short8 s = *(const short8*)(x1_bf + ((size_t)(base + m) << 6) + (c << 3));
        *(short8*)&lx[loff] = s;
    }
    __syncthreads();

    int w = t >> 6, lane = t & 63;
    short8 a[2];
#pragma unroll
    for (int q = 0; q < 2; ++q) a[q] = *(short8*)&lx[((w * 2 + q) * 64 + lane) * 8];

    const short8* bw = (const short8*)fw2;
    floatx4 acc[4];
#pragma unroll
    for (int tt = 0; tt < 4; ++tt) acc[tt] = (floatx4){0.f, 0.f, 0.f, 0.f};
#pragma unroll
    for (int tt = 0; tt < 4; ++tt) {
#pragma unroll
        for (int q = 0; q < 2; ++q) {
            short8 b = bw[(tt * 2 + q) * 64 + lane];
            acc[tt] = __builtin_amdgcn_mfma_f32_16x16x32_bf16(a[q], b, acc[tt], 0, 0, 0);
        }
    }

    int cl = lane & 15, grp = lane >> 4;
#pragma unroll
    for (int tt = 0; tt < 4; ++tt) {
#pragma unroll
        for (int r = 0; r < 4; ++r) {
            int node = base + w * 16 + grp * 4 + r;
            h_bf[(size_t)node * 64 + tt * 16 + cl] = f2bf(acc[tt][r]);
        }
    }

    float as0 = prm[P_AS2 + 0  + cl], as1 = prm[P_AS2 + 16 + cl],
          as2 = prm[P_AS2 + 32 + cl], as3 = prm[P_AS2 + 48 + cl];
    float ad0 = prm[P_AD2 + 0  + cl], ad1 = prm[P_AD2 + 16 + cl],
          ad2 = prm[P_AD2 + 32 + cl], ad3 = prm[P_AD2 + 48 + cl];
#pragma unroll
    for (int r = 0; r < 4; ++r) {
        float sh0 = red16(acc[0][r] * as0 + acc[1][r] * as1);
        float sh1 = red16(acc[2][r] * as2 + acc[3][r] * as3);
        float dh0 = red16(acc[0][r] * ad0 + acc[1][r] * ad1);
        float dh1 = red16(acc[2][r] * ad2 + acc[3][r] * ad3);
        if (cl == 0) {
            int node = base + w * 16 + grp * 4 + r;
            as_[node * 2] = sh0;  as_[node * 2 + 1] = sh1;
            ad_[node * 2] = dh0;  ad_[node * 2 + 1] = dh1;
        }
    }
}

// halving slot-reduction: lane ends with channel k=(lane&7) summed over its
// octet's 8 slots. 7 shfl + 14 sel + 7 add (vs 24/24/7 full butterfly).
// All shuffles convergent.
__device__ __forceinline__ float slot_reduce(float acc[8], int lane) {
    int slot = lane & 7;
    bool b2 = (slot & 4) != 0;
#pragma unroll
    for (int q = 0; q < 4; ++q) {
        float send = b2 ? acc[q] : acc[q + 4];
        float recv = __shfl_xor(send, 4, 64);
        acc[q] = (b2 ? acc[q + 4] : acc[q]) + recv;
    }
    bool b1 = (slot & 2) != 0;
#pragma unroll
    for (int q = 0; q < 2; ++q) {
        float send = b1 ? acc[q] : acc[q + 2];
        float recv = __shfl_xor(send, 2, 64);
        acc[q] = (b1 ? acc[q + 2] : acc[q]) + recv;
    }
    bool b0 = (slot & 1) != 0;
    float send = b0 ? acc[0] : acc[1];
    float recv = __shfl_xor(send, 1, 64);
    return (b0 ? acc[1] : acc[0]) + recv;
}

// ---------------- aggregation core, slot-parallel, SHUFFLE-FREE ----------------
// R10 (confirmed win): each slot lane loads col[e] and as_[c*2+hi] DIRECTLY
// (4B broadcast across the 8 lanes sharing a slot) and recomputes its own
// head's exp. Deletes all round shuffles AND the entire red64: denominator =
// per-lane running sum + 3-op octet xor-reduce. DS ops per node ~31 -> ~10.
__device__ __forceinline__ float agg_core(const unsigned short* __restrict__ h_bf,
                                          const float* __restrict__ as_,
                                          const float* __restrict__ ad_,
                                          const int* __restrict__ col,
                                          int v, int rs, int re, int lane) {
    int deg  = re - rs;
    int slot = lane & 7;
    int cg   = lane >> 3;        // channel group: my 8 channels = cg*8..cg*8+7
    int hi   = cg >> 2;          // head owning my channels
    if (deg <= 64) {
        float advh = ad_[v * 2 + hi];
        const unsigned short* hb = h_bf + (cg << 3);
        int last = re - 1;       // >= rs always (self-loop)
        float acc[8] = {0.f,0.f,0.f,0.f,0.f,0.f,0.f,0.f};
        float sw = 0.f;

        auto block4 = [&](int koff) {
            int ce[4]; float av[4]; uint4 dv[4];
#pragma unroll
            for (int k = 0; k < 4; ++k) {
                int e = rs + koff + k * 8 + slot;
                ce[k] = col[e < last ? e : last];     // clamped: always valid
            }
#pragma unroll
            for (int k = 0; k < 4; ++k)
                dv[k] = *(const uint4*)(hb + ((size_t)ce[k] << 6));
#pragma unroll
            for (int k = 0; k < 4; ++k)
                av[k] = as_[ce[k] * 2 + hi];
#pragma unroll
            for (int k = 0; k < 4; ++k) {
                int e = rs + koff + k * 8 + slot;
                float w = (e <= last) ? __expf(leaky(av[k] + advh)) : 0.f;
                sw += w;
#pragma unroll
                for (int q = 0; q < 4; ++q) {
                    unsigned int dw = (&dv[k].x)[q];
                    acc[2 * q]     = fmaf(w, __uint_as_float(dw << 16),         acc[2 * q]);
                    acc[2 * q + 1] = fmaf(w, __uint_as_float(dw & 0xFFFF0000u), acc[2 * q + 1]);
                }
            }
        };
        block4(0);                       // covers deg <= 32 (99.98% of nodes)
        if (deg > 32) block4(32);        // rare tail, wave-uniform

        // denominator: sum over the octet's 8 slots (3 convergent shuffles)
        sw += __shfl_xor(sw, 1, 64);
        sw += __shfl_xor(sw, 2, 64);
        sw += __shfl_xor(sw, 4, 64);
        float rdh = 1.f / (sw + 1e-16f);

        return slot_reduce(acc, lane) * rdh;
    } else {
        int head = lane >> 5;
        float adv0 = ad_[v * 2], adv1 = ad_[v * 2 + 1];
        float advh = head ? adv1 : adv0;
        float s0 = 0.f, s1 = 0.f;
        for (int e = rs + lane; e < re; e += 64) {
            int s = col[e];
            float2 av = *(const float2*)&as_[s * 2];
            s0 += __expf(leaky(av.x + adv0));
            s1 += __expf(leaky(av.y + adv1));
        }
        s0 = red64(s0); s1 = red64(s1);
        float rdh = 1.f / ((head ? s1 : s0) + 1e-16f);
        float a0 = 0.f;
        for (int e = rs; e < re; ++e) {
            int s = col[e];
            float w = __expf(leaky(as_[s * 2 + head] + advh));
            unsigned short u = h_bf[(size_t)s * 64 + lane];
            a0 = fmaf(w, __uint_as_float(((unsigned int)u) << 16), a0);
        }
        return a0 * rdh;
    }
}

// ---------------- aggregation layer 1 (+bias, BN eval, ELU) -> x1_bf ----------------
__global__ __launch_bounds__(256, 6) void agg1_kernel(const unsigned short* __restrict__ h_bf,
                                                   const float* __restrict__ as_,
                                                   const float* __restrict__ ad_,
                                                   const int* __restrict__ row_start,
                                                   const int* __restrict__ col,
                                                   const float* __restrict__ bias,
                                                   const float* __restrict__ bn_g,
                                                   const float* __restrict__ bn_b,
                                                   const float* __restrict__ bn_m,
                                                   const float* __restrict__ bn_v,
                                                   unsigned short* __restrict__ x1_bf) {
    int t = threadIdx.x, wid = t >> 6, lane = t & 63;
    int v = blockIdx.x * 4 + wid;
    int rs = row_start[v], re = row_start[v + 1];
    float acc = agg_core(h_bf, as_, ad_, col, v, rs, re, lane);
    float r = acc + bias[lane];
    float scale = bn_g[lane] * rsqrtf(bn_v[lane] + BN_EPS);
    r = (r - bn_m[lane]) * scale + bn_b[lane];
    r = r > 0.f ? r : expm1f(r);   // ELU
    x1_bf[(size_t)v * 64 + lane] = f2bf(r);
}

// ---------------- agg layer 2 + JK max + fused projection -> out [N,40] ----------------
__global__ __launch_bounds__(256, 6) void agg2_kernel(const unsigned short* __restrict__ h_bf,
                                                   const float* __restrict__ as_,
                                                   const float* __restrict__ ad_,
                                                   const int* __restrict__ row_start,
                                                   const int* __restrict__ col,
                                                   const float* __restrict__ prm,
                                                   const unsigned short* __restrict__ x1_bf,
                                                   const int* __restrict__ flag,
                                                   void* __restrict__ out) {
    __shared__ float Wfs[2560];      // Wf[c*40+o] natural layout: lanes o stride-1 -> conflict-free
    __shared__ float xsh[4][64];
    int t = threadIdx.x;
#pragma unroll
    for (int i = 0; i < 10; ++i) Wfs[i * 256 + t] = prm[P_WF + i * 256 + t];

    int wid = t >> 6, lane = t & 63;
    int v = blockIdx.x * 4 + wid;
    int rs = row_start[v], re = row_start[v + 1];
    float acc = agg_core(h_bf, as_, ad_, col, v, rs, re, lane);
    float x2 = acc + prm[P_B2 + lane];
    unsigned short u = x1_bf[(size_t)v * 64 + lane];
    float x1v = __uint_as_float(((unsigned int)u) << 16);
    xsh[wid][lane] = fmaxf(x1v, x2);   // JumpingKnowledge max
    __syncthreads();

    if (t < 160) {                     // 4 nodes x 40 outputs
        int n = t / 40, o = t - n * 40;
        float po = 0.f;
#pragma unroll
        for (int c = 0; c < 64; c += 4) {
            po = fmaf(xsh[n][c],     Wfs[c * 40 + o],       po);
            po = fmaf(xsh[n][c + 1], Wfs[(c + 1) * 40 + o], po);
            po = fmaf(xsh[n][c + 2], Wfs[(c + 2) * 40 + o], po);
            po = fmaf(xsh[n][c + 3], Wfs[(c + 3) * 40 + o], po);
        }
        float r = po + prm[P_BF + o];
        size_t idx = (size_t)(blockIdx.x * 4 + n) * 40 + o;
        if (*flag) ((float*)out)[idx] = r;
        else ((__hip_bfloat16*)out)[idx] = __float2bfloat16(r);
    }
}

extern "C" void kernel_launch(void* const* d_in, const int* in_sizes, int n_in,
                              void* d_out, int out_size, void* d_ws, size_t ws_size,
                              hipStream_t stream) {
    (void)in_sizes; (void)n_in; (void)out_size; (void)ws_size;
    const void* node_feat = d_in[0];
    const int*  edge_idx  = (const int*)d_in[1];

    char* ws = (char*)d_ws;
    size_t off = 0;
    auto alloc = [&](size_t bytes) -> void* {
        void* p = ws + off;
        off += (bytes + 255) & ~(size_t)255;
        return p;
    };
    unsigned short* h_bf  = (unsigned short*)alloc((size_t)N_NODES * 64 * 2);  // 12.8 MB
    unsigned short* x1_bf = (unsigned short*)alloc((size_t)N_NODES * 64 * 2);  // 12.8 MB
    float* as_ = (float*)alloc((size_t)N_NODES * 2 * 4);
    float* ad_ = (float*)alloc((size_t)N_NODES * 2 * 4);
    int* deg       = (int*)alloc((size_t)N_NODES * 4);
    int* row_start = (int*)alloc((size_t)(N_NODES + 1) * 4);
    int4* rank4    = (int4*)alloc((size_t)EQ4 * 16);        // 6.4 MB (32-bit ranks)
    int* col       = (int*)alloc((size_t)ETOT * 4);         // 6.8 MB
    int* bsum      = (int*)alloc((size_t)NB_SCAN * 4);
    int* boff      = (int*)alloc((size_t)NB_SCAN * 4);
    float* prm     = (float*)alloc((size_t)P_TOT * 4);
    unsigned short* fw1 = (unsigned short*)alloc(8192 * 2);
    unsigned short* fw2 = (unsigned short*)alloc(4096 * 2);
    int* flag      = (int*)alloc(256);

    detect_kernel<<<1, 64, 0, stream>>>((const unsigned short*)node_feat, flag);
    CvtArgs ca;
    const int lens[14] = {8192, 64, 64, 64, 64, 64, 64, 64, 4096, 64, 64, 64, 2560, 40};
    for (int i = 0; i < 14; ++i) { ca.ptr[i] = d_in[i + 2]; ca.len[i] = lens[i]; }
    cvt_params_kernel<<<(P_TOT + 255) / 256, 256, 0, stream>>>(ca, flag, prm);
    build_frags_kernel<<<48, 256, 0, stream>>>(prm, fw1, fw2);

    // CSR build: rank-based (R12). hist computes per-edge rank via atomic
    // return; scatter is atomic-free.
    hipMemsetAsync(deg, 0, (size_t)N_NODES * 4, stream);
    histrank_kernel<<<NB_EQ4, 256, 0, stream>>>(edge_idx, deg, rank4);
    scanA_kernel<<<NB_SCAN, 256, 0, stream>>>(deg, bsum);
    scanB_kernel<<<1, 512, 0, stream>>>(bsum, boff, row_start);
    scanC_kernel<<<NB_SCAN, 256, 0, stream>>>(deg, boff, row_start, col);
    scatter_kernel<<<NB_EQ4, 256, 0, stream>>>(edge_idx, rank4, row_start, col);

    gemm1_kernel<<<N_NODES / 32, 128, 0, stream>>>(node_feat, fw1, prm, flag,
                                                   h_bf, as_, ad_);
    agg1_kernel<<<N_NODES / 4, 256, 0, stream>>>(h_bf, as_, ad_, row_start, col,
                                                 prm + P_B1, prm + P_BNG, prm + P_BNB,
                                                 prm + P_BNM, prm + P_BNV, x1_bf);
    gemm2_kernel<<<N_NODES / 32, 128, 0, stream>>>(x1_bf, fw2, prm,
                                                   h_bf, as_, ad_);
    agg2_kernel<<<N_NODES / 4, 256, 0, stream>>>(h_bf, as_, ad_, row_start, col,
                                                 prm, x1_bf, flag, d_out);
}

// Round 7
// 378.138 us; speedup vs baseline: 1.1232x; 1.0113x over previous
//
#include <hip/hip_runtime.h>
#include <hip/hip_bf16.h>

#define N_NODES 100000
#define E_EDGES 1600000
#define ETOT    1700000   // E + N self-loops
#define NB_SCAN 391       // ceil(N/256)
#define EQ4     400000    // E_EDGES / 4
#define NB_EQ4  1563      // ceil(EQ4 / 256)
#define F_IN    128
#define HC      64
#define OUT_C   40
#define NEG_SLOPE 0.2f
#define BN_EPS  1e-5f

// fp32 param block layout (element offsets)
#define P_W1   0
#define P_AS1  8192
#define P_AD1  8256
#define P_B1   8320
#define P_BNG  8384
#define P_BNB  8448
#define P_BNM  8512
#define P_BNV  8576
#define P_W2   8640
#define P_AS2  12736
#define P_AD2  12800
#define P_B2   12864
#define P_WF   12928
#define P_BF   15488
#define P_TOT  15528

typedef __attribute__((ext_vector_type(8))) short short8;
typedef __attribute__((ext_vector_type(4))) float floatx4;

__device__ __forceinline__ unsigned short f2bf(float f) {   // RNE fp32->bf16
    unsigned int u = __float_as_uint(f);
    unsigned int r = u + 0x7FFFu + ((u >> 16) & 1u);
    return (unsigned short)(r >> 16);
}

// ---------------- dtype detection ----------------
__global__ __launch_bounds__(64) void detect_kernel(const unsigned short* __restrict__ x,
                                                    int* __restrict__ flag) {
    int t = threadIdx.x;
    bool huge = false;
#pragma unroll
    for (int i = 0; i < 4; ++i) {
        unsigned short u = x[(t * 4 + i) * 2];
        float v = __uint_as_float(((unsigned int)u) << 16);
        if (!(fabsf(v) < 1e4f)) huge = true;
    }
    unsigned long long b = __ballot(huge);
    if (t == 0) *flag = (b != 0ull) ? 1 : 0;             // 1 => fp32 tensors
}

// ---------------- small-param conversion to fp32 ----------------
struct CvtArgs { const void* ptr[14]; int len[14]; };

__global__ __launch_bounds__(256) void cvt_params_kernel(CvtArgs a,
                                                         const int* __restrict__ flag,
                                                         float* __restrict__ dst) {
    int f = *flag;
    int i = blockIdx.x * 256 + threadIdx.x;
    if (i >= P_TOT) return;
    int k = 0, off = 0;
    while (i >= off + a.len[k]) { off += a.len[k]; ++k; }
    int j = i - off;
    float v = f ? ((const float*)a.ptr[k])[j]
                : __bfloat162float(((const __hip_bfloat16*)a.ptr[k])[j]);
    dst[i] = v;
}

// ---------------- W1/W2 -> bf16 MFMA B-fragment order ----------------
__global__ __launch_bounds__(256) void build_frags_kernel(const float* __restrict__ prm,
                                                          unsigned short* __restrict__ fw1,
                                                          unsigned short* __restrict__ fw2) {
    int i = blockIdx.x * 256 + threadIdx.x;
    if (i < 8192) {
        int j = i & 7, l = (i >> 3) & 63, q = (i >> 9) & 3, t = i >> 11;
        int k = q * 32 + (l >> 4) * 8 + j;
        int n = t * 16 + (l & 15);
        fw1[i] = f2bf(prm[P_W1 + k * 64 + n]);
    } else if (i < 12288) {
        int f = i - 8192;
        int j = f & 7, l = (f >> 3) & 63, q = (f >> 9) & 1, t = f >> 10;
        int k = q * 32 + (l >> 4) * 8 + j;
        int n = t * 16 + (l & 15);
        fw2[f] = f2bf(prm[P_W2 + k * 64 + n]);
    }
}

// ---------------- CSR build, R12 (confirmed win): rank-based, atomic-free ----------------
__global__ __launch_bounds__(256) void histrank_kernel(const int* __restrict__ ei,
                                                       int* __restrict__ deg,
                                                       int4* __restrict__ rank4) {
    int i4 = blockIdx.x * 256 + threadIdx.x;
    if (i4 >= EQ4) return;
    const unsigned long long* dst2 = (const unsigned long long*)(ei + E_EDGES);
    unsigned long long p0 = __builtin_nontemporal_load(&dst2[i4 * 2]);
    unsigned long long p1 = __builtin_nontemporal_load(&dst2[i4 * 2 + 1]);
    int d0 = (int)(p0 & 0xFFFFFFFFull), d1 = (int)(p0 >> 32);
    int d2 = (int)(p1 & 0xFFFFFFFFull), d3 = (int)(p1 >> 32);
    int4 r;
    r.x = atomicAdd(&deg[d0], 1);     // 4 independent atomics, all in flight
    r.y = atomicAdd(&deg[d1], 1);
    r.z = atomicAdd(&deg[d2], 1);
    r.w = atomicAdd(&deg[d3], 1);
    rank4[i4] = r;                    // coalesced 16B store
}

// parallel scan; degree counted as deg[i]+1 (self-loop folded in)
__global__ __launch_bounds__(256) void scanA_kernel(const int* __restrict__ deg,
                                                    int* __restrict__ bsum) {
    __shared__ int sm[256];
    int t = threadIdx.x;
    int i = blockIdx.x * 256 + t;
    sm[t] = (i < N_NODES) ? deg[i] + 1 : 0;
    __syncthreads();
    for (int off = 128; off > 0; off >>= 1) {
        if (t < off) sm[t] += sm[t + off];
        __syncthreads();
    }
    if (t == 0) bsum[blockIdx.x] = sm[0];
}

__global__ __launch_bounds__(512) void scanB_kernel(const int* __restrict__ bsum,
                                                    int* __restrict__ boff,
                                                    int* __restrict__ row_start) {
    __shared__ int sm[512];
    int t = threadIdx.x;
    int v = (t < NB_SCAN) ? bsum[t] : 0;
    sm[t] = v;
    __syncthreads();
    for (int off = 1; off < 512; off <<= 1) {
        int o = (t >= off) ? sm[t - off] : 0;
        __syncthreads();
        sm[t] += o;
        __syncthreads();
    }
    if (t < NB_SCAN) boff[t] = sm[t] - v;
    if (t == NB_SCAN - 1) row_start[N_NODES] = sm[t];   // == ETOT
}

__global__ __launch_bounds__(256) void scanC_kernel(const int* __restrict__ deg,
                                                    const int* __restrict__ boff,
                                                    int* __restrict__ row_start,
                                                    int* __restrict__ col) {
    __shared__ int sm[256];
    int t = threadIdx.x;
    int i = blockIdx.x * 256 + t;
    int v = (i < N_NODES) ? deg[i] + 1 : 0;
    sm[t] = v;
    __syncthreads();
    for (int off = 1; off < 256; off <<= 1) {
        int o = (t >= off) ? sm[t - off] : 0;
        __syncthreads();
        sm[t] += o;
        __syncthreads();
    }
    if (i < N_NODES) {
        int excl = sm[t] - v + boff[blockIdx.x];
        row_start[i] = excl;
        col[excl]    = i;              // slot 0 = self-loop
    }
}

// ---------------- atomic-free scatter: pure stream + independent stores ----------------
__global__ __launch_bounds__(256) void scatter_kernel(const int* __restrict__ ei,
                                                      const int4* __restrict__ rank4,
                                                      const int* __restrict__ row_start,
                                                      int* __restrict__ col) {
    int i4 = blockIdx.x * 256 + threadIdx.x;
    if (i4 >= EQ4) return;
    const unsigned long long* dst2 = (const unsigned long long*)(ei + E_EDGES);
    const unsigned long long* src2 = (const unsigned long long*)ei;
    unsigned long long p0 = __builtin_nontemporal_load(&dst2[i4 * 2]);
    unsigned long long p1 = __builtin_nontemporal_load(&dst2[i4 * 2 + 1]);
    unsigned long long q0 = __builtin_nontemporal_load(&src2[i4 * 2]);
    unsigned long long q1 = __builtin_nontemporal_load(&src2[i4 * 2 + 1]);
    int4 r = rank4[i4];
    int d0 = (int)(p0 & 0xFFFFFFFFull), d1 = (int)(p0 >> 32);
    int d2 = (int)(p1 & 0xFFFFFFFFull), d3 = (int)(p1 >> 32);
    int s0 = (int)(q0 & 0xFFFFFFFFull), s1 = (int)(q0 >> 32);
    int s2 = (int)(q1 & 0xFFFFFFFFull), s3 = (int)(q1 >> 32);
    int b0 = row_start[d0];            // 4 independent gathers (L2-resident)
    int b1 = row_start[d1];
    int b2 = row_start[d2];
    int b3 = row_start[d3];
    col[b0 + 1 + r.x] = s0;            // 4 independent stores, no round-trip
    col[b1 + 1 + r.y] = s1;
    col[b2 + 1 + r.z] = s2;
    col[b3 + 1 + r.w] = s3;
}

__device__ __forceinline__ float leaky(float v) { return v > 0.f ? v : NEG_SLOPE * v; }

__device__ __forceinline__ float red64(float v) {
#pragma unroll
    for (int off = 32; off > 0; off >>= 1) v += __shfl_xor(v, off, 64);
    return v;
}
__device__ __forceinline__ float red16(float v) {
#pragma unroll
    for (int off = 8; off > 0; off >>= 1) v += __shfl_xor(v, off, 64);
    return v;
}

// ---------------- MFMA GEMM 1: h_bf[N,64] = x[N,128] @ W1, + fused alpha ----------------
__global__ __launch_bounds__(128) void gemm1_kernel(const void* __restrict__ x,
                                                    const unsigned short* __restrict__ fw1,
                                                    const float* __restrict__ prm,
                                                    const int* __restrict__ flag,
                                                    unsigned short* __restrict__ h_bf,
                                                    float* __restrict__ as_,
                                                    float* __restrict__ ad_) {
    __shared__ short lx[2 * 4 * 64 * 8];   // 8 KB
    int t = threadIdx.x;
    int f = *flag;
    int base = blockIdx.x * 32;

#pragma unroll
    for (int i = 0; i < 4; ++i) {
        int cid = i * 128 + t;
        int m = cid >> 4, c = cid & 15;
        int q = c >> 2, g = c & 3;
        int loff = (((m >> 4) * 4 + q) * 64 + g * 16 + (m & 15)) * 8;
        short8 s;
        if (f) {
            const float4* p = (const float4*)((const float*)x + ((size_t)(base + m) << 7) + (c << 3));
            float4 u0 = p[0], u1 = p[1];
            s[0] = (short)f2bf(u0.x); s[1] = (short)f2bf(u0.y);
            s[2] = (short)f2bf(u0.z); s[3] = (short)f2bf(u0.w);
            s[4] = (short)f2bf(u1.x); s[5] = (short)f2bf(u1.y);
            s[6] = (short)f2bf(u1.z); s[7] = (short)f2bf(u1.w);
        } else {
            s = *(const short8*)((const unsigned short*)x + ((size_t)(base + m) << 7) + (c << 3));
        }
        *(short8*)&lx[loff] = s;
    }
    __syncthreads();

    int w = t >> 6, lane = t & 63;
    short8 a[4];
#pragma unroll
    for (int q = 0; q < 4; ++q) a[q] = *(short8*)&lx[((w * 4 + q) * 64 + lane) * 8];

    const short8* bw = (const short8*)fw1;
    floatx4 acc[4];
#pragma unroll
    for (int tt = 0; tt < 4; ++tt) acc[tt] = (floatx4){0.f, 0.f, 0.f, 0.f};
#pragma unroll
    for (int tt = 0; tt < 4; ++tt) {
#pragma unroll
        for (int q = 0; q < 4; ++q) {
            short8 b = bw[(tt * 4 + q) * 64 + lane];
            acc[tt] = __builtin_amdgcn_mfma_f32_16x16x32_bf16(a[q], b, acc[tt], 0, 0, 0);
        }
    }

    int cl = lane & 15, grp = lane >> 4;
#pragma unroll
    for (int tt = 0; tt < 4; ++tt) {
#pragma unroll
        for (int r = 0; r < 4; ++r) {
            int node = base + w * 16 + grp * 4 + r;
            h_bf[(size_t)node * 64 + tt * 16 + cl] = f2bf(acc[tt][r]);
        }
    }

    float as0 = prm[P_AS1 + 0  + cl], as1 = prm[P_AS1 + 16 + cl],
          as2 = prm[P_AS1 + 32 + cl], as3 = prm[P_AS1 + 48 + cl];
    float ad0 = prm[P_AD1 + 0  + cl], ad1 = prm[P_AD1 + 16 + cl],
          ad2 = prm[P_AD1 + 32 + cl], ad3 = prm[P_AD1 + 48 + cl];
#pragma unroll
    for (int r = 0; r < 4; ++r) {
        float sh0 = red16(acc[0][r] * as0 + acc[1][r] * as1);
        float sh1 = red16(acc[2][r] * as2 + acc[3][r] * as3);
        float dh0 = red16(acc[0][r] * ad0 + acc[1][r] * ad1);
        float dh1 = red16(acc[2][r] * ad2 + acc[3][r] * ad3);
        if (cl == 0) {
            int node = base + w * 16 + grp * 4 + r;
            as_[node * 2] = sh0;  as_[node * 2 + 1] = sh1;
            ad_[node * 2] = dh0;  ad_[node * 2 + 1] = dh1;
        }
    }
}

// ---------------- MFMA GEMM 2: h_bf = x1_bf[N,64] @ W2, + fused alpha ----------------
__global__ __launch_bounds__(128) void gemm2_kernel(const unsigned short* __restrict__ x1_bf,
                                                    const unsigned short* __restrict__ fw2,
                                                    const float* __restrict__ prm,
                                                    unsigned short* __restrict__ h_bf,
                                                    float* __restrict__ as_,
                                                    float* __restrict__ ad_) {
    __shared__ short lx[2 * 2 * 64 * 8];   // 4 KB
    int t = threadIdx.x;
    int base = blockIdx.x * 32;

#pragma unroll
    for (int i = 0; i < 2; ++i) {
        int cid = i * 128 + t;
        int m = cid >> 3, c = cid & 7;
        int q = c >> 2, g = c & 3;
        int loff = (((m >> 4) * 2 + q) * 64 + g * 16 + (m & 15)) * 8;
        short8 s = *(const short8*)(x1_bf + ((size_t)(base + m) << 6) + (c << 3));
        *(short8*)&lx[loff] = s;
    }
    __syncthreads();

    int w = t >> 6, lane = t & 63;
    short8 a[2];
#pragma unroll
    for (int q = 0; q < 2; ++q) a[q] = *(short8*)&lx[((w * 2 + q) * 64 + lane) * 8];

    const short8* bw = (const short8*)fw2;
    floatx4 acc[4];
#pragma unroll
    for (int tt = 0; tt < 4; ++tt) acc[tt] = (floatx4){0.f, 0.f, 0.f, 0.f};
#pragma unroll
    for (int tt = 0; tt < 4; ++tt) {
#pragma unroll
        for (int q = 0; q < 2; ++q) {
            short8 b = bw[(tt * 2 + q) * 64 + lane];
            acc[tt] = __builtin_amdgcn_mfma_f32_16x16x32_bf16(a[q], b, acc[tt], 0, 0, 0);
        }
    }

    int cl = lane & 15, grp = lane >> 4;
#pragma unroll
    for (int tt = 0; tt < 4; ++tt) {
#pragma unroll
        for (int r = 0; r < 4; ++r) {
            int node = base + w * 16 + grp * 4 + r;
            h_bf[(size_t)node * 64 + tt * 16 + cl] = f2bf(acc[tt][r]);
        }
    }

    float as0 = prm[P_AS2 + 0  + cl], as1 = prm[P_AS2 + 16 + cl],
          as2 = prm[P_AS2 + 32 + cl], as3 = prm[P_AS2 + 48 + cl];
    float ad0 = prm[P_AD2 + 0  + cl], ad1 = prm[P_AD2 + 16 + cl],
          ad2 = prm[P_AD2 + 32 + cl], ad3 = prm[P_AD2 + 48 + cl];
#pragma unroll
    for (int r = 0; r < 4; ++r) {
        float sh0 = red16(acc[0][r] * as0 + acc[1][r] * as1);
        float sh1 = red16(acc[2][r] * as2 + acc[3][r] * as3);
        float dh0 = red16(acc[0][r] * ad0 + acc[1][r] * ad1);
        float dh1 = red16(acc[2][r] * ad2 + acc[3][r] * ad3);
        if (cl == 0) {
            int node = base + w * 16 + grp * 4 + r;
            as_[node * 2] = sh0;  as_[node * 2 + 1] = sh1;
            ad_[node * 2] = dh0;  ad_[node * 2 + 1] = dh1;
        }
    }
}

// halving slot-reduction: lane ends with channel k=(lane&7) summed over its
// octet's 8 slots. 7 shfl + 14 sel + 7 add (vs 24/24/7 full butterfly).
// All shuffles convergent.
__device__ __forceinline__ float slot_reduce(float acc[8], int lane) {
    int slot = lane & 7;
    bool b2 = (slot & 4) != 0;
#pragma unroll
    for (int q = 0; q < 4; ++q) {
        float send = b2 ? acc[q] : acc[q + 4];
        float recv = __shfl_xor(send, 4, 64);
        acc[q] = (b2 ? acc[q + 4] : acc[q]) + recv;
    }
    bool b1 = (slot & 2) != 0;
#pragma unroll
    for (int q = 0; q < 2; ++q) {
        float send = b1 ? acc[q] : acc[q + 2];
        float recv = __shfl_xor(send, 2, 64);
        acc[q] = (b1 ? acc[q + 2] : acc[q]) + recv;
    }
    bool b0 = (slot & 1) != 0;
    float send = b0 ? acc[0] : acc[1];
    float recv = __shfl_xor(send, 1, 64);
    return (b0 ? acc[1] : acc[0]) + recv;
}

// ---------------- aggregation core, slot-parallel, degree-adaptive ----------------
// R10 (win): shuffle-free slot loads. R13: degree-adaptive round count.
// R6 PMC: VALUBusy 68% -- the fixed block4 always runs 32 slots while mean
// row length is 17, wasting ~1.9x of the unpack+fma+exp work on w=0 slots.
// Tiered dispatch {1,2,3,4,4+4} rounds by deg (wave-uniform branch, one node
// per wave => no divergence). E[rounds] ~ 2.56 vs fixed 4 (-36% VALU).
// Batched-load structure inside each tier preserved (loads first, fma after).
#define AGG_ROUNDS(KOFF, NK)                                                   \
    {                                                                          \
        int ce[NK]; float av[NK]; uint4 dv[NK];                                \
        _Pragma("unroll")                                                      \
        for (int k = 0; k < NK; ++k) {                                         \
            int e = rs + (KOFF) + k * 8 + slot;                                \
            ce[k] = col[e < last ? e : last];                                  \
        }                                                                      \
        _Pragma("unroll")                                                      \
        for (int k = 0; k < NK; ++k)                                           \
            dv[k] = *(const uint4*)(hb + ((size_t)ce[k] << 6));                \
        _Pragma("unroll")                                                      \
        for (int k = 0; k < NK; ++k)                                           \
            av[k] = as_[ce[k] * 2 + hi];                                       \
        _Pragma("unroll")                                                      \
        for (int k = 0; k < NK; ++k) {                                         \
            int e = rs + (KOFF) + k * 8 + slot;                                \
            float w = (e <= last) ? __expf(leaky(av[k] + advh)) : 0.f;         \
            sw += w;                                                           \
            _Pragma("unroll")                                                  \
            for (int q = 0; q < 4; ++q) {                                      \
                unsigned int dw = (&dv[k].x)[q];                               \
                acc[2 * q]     = fmaf(w, __uint_as_float(dw << 16),          acc[2 * q]);     \
                acc[2 * q + 1] = fmaf(w, __uint_as_float(dw & 0xFFFF0000u),  acc[2 * q + 1]); \
            }                                                                  \
        }                                                                      \
    }

__device__ __forceinline__ float agg_core(const unsigned short* __restrict__ h_bf,
                                          const float* __restrict__ as_,
                                          const float* __restrict__ ad_,
                                          const int* __restrict__ col,
                                          int v, int rs, int re, int lane) {
    int deg  = re - rs;
    int slot = lane & 7;
    int cg   = lane >> 3;        // channel group: my 8 channels = cg*8..cg*8+7
    int hi   = cg >> 2;          // head owning my channels
    if (deg <= 64) {
        float advh = ad_[v * 2 + hi];
        const unsigned short* hb = h_bf + (cg << 3);
        int last = re - 1;       // >= rs always (self-loop)
        float acc[8] = {0.f,0.f,0.f,0.f,0.f,0.f,0.f,0.f};
        float sw = 0.f;

        if (deg <= 8) {
            AGG_ROUNDS(0, 1)
        } else if (deg <= 16) {
            AGG_ROUNDS(0, 2)
        } else if (deg <= 24) {
            AGG_ROUNDS(0, 3)
        } else {
            AGG_ROUNDS(0, 4)
            if (deg > 32) AGG_ROUNDS(32, 4)
        }

        // denominator: sum over the octet's 8 slots (3 convergent shuffles)
        sw += __shfl_xor(sw, 1, 64);
        sw += __shfl_xor(sw, 2, 64);
        sw += __shfl_xor(sw, 4, 64);
        float rdh = 1.f / (sw + 1e-16f);

        return slot_reduce(acc, lane) * rdh;
    } else {
        int head = lane >> 5;
        float adv0 = ad_[v * 2], adv1 = ad_[v * 2 + 1];
        float advh = head ? adv1 : adv0;
        float s0 = 0.f, s1 = 0.f;
        for (int e = rs + lane; e < re; e += 64) {
            int s = col[e];
            float2 av = *(const float2*)&as_[s * 2];
            s0 += __expf(leaky(av.x + adv0));
            s1 += __expf(leaky(av.y + adv1));
        }
        s0 = red64(s0); s1 = red64(s1);
        float rdh = 1.f / ((head ? s1 : s0) + 1e-16f);
        float a0 = 0.f;
        for (int e = rs; e < re; ++e) {
            int s = col[e];
            float w = __expf(leaky(as_[s * 2 + head] + advh));
            unsigned short u = h_bf[(size_t)s * 64 + lane];
            a0 = fmaf(w, __uint_as_float(((unsigned int)u) << 16), a0);
        }
        return a0 * rdh;
    }
}

// ---------------- aggregation layer 1 (+bias, BN eval, ELU) -> x1_bf ----------------
__global__ __launch_bounds__(256, 6) void agg1_kernel(const unsigned short* __restrict__ h_bf,
                                                   const float* __restrict__ as_,
                                                   const float* __restrict__ ad_,
                                                   const int* __restrict__ row_start,
                                                   const int* __restrict__ col,
                                                   const float* __restrict__ bias,
                                                   const float* __restrict__ bn_g,
                                                   const float* __restrict__ bn_b,
                                                   const float* __restrict__ bn_m,
                                                   const float* __restrict__ bn_v,
                                                   unsigned short* __restrict__ x1_bf) {
    int t = threadIdx.x, wid = t >> 6, lane = t & 63;
    int v = blockIdx.x * 4 + wid;
    int rs = row_start[v], re = row_start[v + 1];
    float acc = agg_core(h_bf, as_, ad_, col, v, rs, re, lane);
    float r = acc + bias[lane];
    float scale = bn_g[lane] * rsqrtf(bn_v[lane] + BN_EPS);
    r = (r - bn_m[lane]) * scale + bn_b[lane];
    r = r > 0.f ? r : expm1f(r);   // ELU
    x1_bf[(size_t)v * 64 + lane] = f2bf(r);
}

// ---------------- agg layer 2 + JK max + fused projection -> out [N,40] ----------------
__global__ __launch_bounds__(256, 6) void agg2_kernel(const unsigned short* __restrict__ h_bf,
                                                   const float* __restrict__ as_,
                                                   const float* __restrict__ ad_,
                                                   const int* __restrict__ row_start,
                                                   const int* __restrict__ col,
                                                   const float* __restrict__ prm,
                                                   const unsigned short* __restrict__ x1_bf,
                                                   const int* __restrict__ flag,
                                                   void* __restrict__ out) {
    __shared__ float Wfs[2560];      // Wf[c*40+o] natural layout: lanes o stride-1 -> conflict-free
    __shared__ float xsh[4][64];
    int t = threadIdx.x;
#pragma unroll
    for (int i = 0; i < 10; ++i) Wfs[i * 256 + t] = prm[P_WF + i * 256 + t];

    int wid = t >> 6, lane = t & 63;
    int v = blockIdx.x * 4 + wid;
    int rs = row_start[v], re = row_start[v + 1];
    float acc = agg_core(h_bf, as_, ad_, col, v, rs, re, lane);
    float x2 = acc + prm[P_B2 + lane];
    unsigned short u = x1_bf[(size_t)v * 64 + lane];
    float x1v = __uint_as_float(((unsigned int)u) << 16);
    xsh[wid][lane] = fmaxf(x1v, x2);   // JumpingKnowledge max
    __syncthreads();

    if (t < 160) {                     // 4 nodes x 40 outputs
        int n = t / 40, o = t - n * 40;
        float po = 0.f;
#pragma unroll
        for (int c = 0; c < 64; c += 4) {
            po = fmaf(xsh[n][c],     Wfs[c * 40 + o],       po);
            po = fmaf(xsh[n][c + 1], Wfs[(c + 1) * 40 + o], po);
            po = fmaf(xsh[n][c + 2], Wfs[(c + 2) * 40 + o], po);
            po = fmaf(xsh[n][c + 3], Wfs[(c + 3) * 40 + o], po);
        }
        float r = po + prm[P_BF + o];
        size_t idx = (size_t)(blockIdx.x * 4 + n) * 40 + o;
        if (*flag) ((float*)out)[idx] = r;
        else ((__hip_bfloat16*)out)[idx] = __float2bfloat16(r);
    }
}

extern "C" void kernel_launch(void* const* d_in, const int* in_sizes, int n_in,
                              void* d_out, int out_size, void* d_ws, size_t ws_size,
                              hipStream_t stream) {
    (void)in_sizes; (void)n_in; (void)out_size; (void)ws_size;
    const void* node_feat = d_in[0];
    const int*  edge_idx  = (const int*)d_in[1];

    char* ws = (char*)d_ws;
    size_t off = 0;
    auto alloc = [&](size_t bytes) -> void* {
        void* p = ws + off;
        off += (bytes + 255) & ~(size_t)255;
        return p;
    };
    unsigned short* h_bf  = (unsigned short*)alloc((size_t)N_NODES * 64 * 2);  // 12.8 MB
    unsigned short* x1_bf = (unsigned short*)alloc((size_t)N_NODES * 64 * 2);  // 12.8 MB
    float* as_ = (float*)alloc((size_t)N_NODES * 2 * 4);
    float* ad_ = (float*)alloc((size_t)N_NODES * 2 * 4);
    int* deg       = (int*)alloc((size_t)N_NODES * 4);
    int* row_start = (int*)alloc((size_t)(N_NODES + 1) * 4);
    int4* rank4    = (int4*)alloc((size_t)EQ4 * 16);        // 6.4 MB (32-bit ranks)
    int* col       = (int*)alloc((size_t)ETOT * 4);         // 6.8 MB
    int* bsum      = (int*)alloc((size_t)NB_SCAN * 4);
    int* boff      = (int*)alloc((size_t)NB_SCAN * 4);
    float* prm     = (float*)alloc((size_t)P_TOT * 4);
    unsigned short* fw1 = (unsigned short*)alloc(8192 * 2);
    unsigned short* fw2 = (unsigned short*)alloc(4096 * 2);
    int* flag      = (int*)alloc(256);

    detect_kernel<<<1, 64, 0, stream>>>((const unsigned short*)node_feat, flag);
    CvtArgs ca;
    const int lens[14] = {8192, 64, 64, 64, 64, 64, 64, 64, 4096, 64, 64, 64, 2560, 40};
    for (int i = 0; i < 14; ++i) { ca.ptr[i] = d_in[i + 2]; ca.len[i] = lens[i]; }
    cvt_params_kernel<<<(P_TOT + 255) / 256, 256, 0, stream>>>(ca, flag, prm);
    build_frags_kernel<<<48, 256, 0, stream>>>(prm, fw1, fw2);

    // CSR build: rank-based (R12). hist computes per-edge rank via atomic
    // return; scatter is atomic-free.
    hipMemsetAsync(deg, 0, (size_t)N_NODES * 4, stream);
    histrank_kernel<<<NB_EQ4, 256, 0, stream>>>(edge_idx, deg, rank4);
    scanA_kernel<<<NB_SCAN, 256, 0, stream>>>(deg, bsum);
    scanB_kernel<<<1, 512, 0, stream>>>(bsum, boff, row_start);
    scanC_kernel<<<NB_SCAN, 256, 0, stream>>>(deg, boff, row_start, col);
    scatter_kernel<<<NB_EQ4, 256, 0, stream>>>(edge_idx, rank4, row_start, col);

    gemm1_kernel<<<N_NODES / 32, 128, 0, stream>>>(node_feat, fw1, prm, flag,
                                                   h_bf, as_, ad_);
    agg1_kernel<<<N_NODES / 4, 256, 0, stream>>>(h_bf, as_, ad_, row_start, col,
                                                 prm + P_B1, prm + P_BNG, prm + P_BNB,
                                                 prm + P_BNM, prm + P_BNV, x1_bf);
    gemm2_kernel<<<N_NODES / 32, 128, 0, stream>>>(x1_bf, fw2, prm,
                                                   h_bf, as_, ad_);
    agg2_kernel<<<N_NODES / 4, 256, 0, stream>>>(h_bf, as_, ad_, row_start, col,
                                                 prm, x1_bf, flag, d_out);
}